// Round 14
// baseline (81.227 us; speedup 1.0000x reference)
//
#include <hip/hip_runtime.h>
#include <math.h>

// B=2, L=512, C=768, C/3=256, pairDim=128
// ws: mo [2,32,512,64] f16 (4 MB) | mt same (4 MB) | W1H f16 frag-packed 128 KB
// k2: 32l x 32m tiles (512 blocks), in-place sc scratch in wave's dead raw region.

typedef __attribute__((ext_vector_type(8))) _Float16 half8;
typedef __attribute__((ext_vector_type(4))) _Float16 half4;
typedef __attribute__((ext_vector_type(4))) float f32x4;

#define MFMA_F16(a,b,c) __builtin_amdgcn_mfma_f32_16x16x32_f16((a),(b),(c),0,0,0)

static __device__ inline unsigned pack2f16(float a, float b) {
    _Float16 ha = (_Float16)a, hb = (_Float16)b;
    unsigned short ua = __builtin_bit_cast(unsigned short, ha);
    unsigned short ub = __builtin_bit_cast(unsigned short, hb);
    return (unsigned)ua | ((unsigned)ub << 16);
}

static __device__ inline half8 cvt8(float4 u, float4 v) {
    half8 h;
    h[0] = (_Float16)u.x; h[1] = (_Float16)u.y; h[2] = (_Float16)u.z; h[3] = (_Float16)u.w;
    h[4] = (_Float16)v.x; h[5] = (_Float16)v.y; h[6] = (_Float16)v.z; h[7] = (_Float16)v.w;
    return h;
}

// k0: W1 [256 j][256 i] f32 -> W1H f16 B-frag order [nt][ks][lane][8]
__global__ __launch_bounds__(256) void k0_pack(const float* __restrict__ W1, _Float16* __restrict__ W1H)
{
    int flat8 = blockIdx.x * 256 + threadIdx.x;   // 0..8191 (8-elem chunks)
    int j  = flat8 >> 5, i8 = flat8 & 31;
    int nt = j >> 4, lr = j & 15, ks = i8 >> 2, lk = i8 & 3;
    const float4* src = (const float4*)(W1 + (size_t)j * 256 + (size_t)i8 * 8);
    half8 h = cvt8(src[0], src[1]);
    *(half8*)(W1H + (((size_t)(nt * 8 + ks) * 64) + lk * 16 + lr) * 8) = h;
}

// k1 (R13 verbatim): 512 blocks x 256 threads; block handles rows l0, l0+1 of batch b.
__global__ __launch_bounds__(256) void k1_rowstage2(
    const float* __restrict__ x, const float* __restrict__ ln_w, const float* __restrict__ ln_b,
    const _Float16* __restrict__ W1H, const float* __restrict__ b1,
    const float* __restrict__ Wa, const float* __restrict__ ba,
    _Float16* __restrict__ mo_g, _Float16* __restrict__ mt_g)
{
    const int blk = blockIdx.x;
    const int b   = blk >> 8;
    const int l0  = (blk & 255) << 1;    // 2 rows
    const int tid = threadIdx.x;
    const int w   = tid >> 6;
    const int lane = tid & 63;
    const int lr  = lane & 15;
    const int lk  = lane >> 4;

    __shared__ _Float16 hs16[16 * 280];  // A rows m=r*3+k (6 used; 6-15 garbage, D-rows unread)
    __shared__ float ts2[2][776];
    __shared__ float mos2[2][2176];

    half8 waf[2];
    #pragma unroll
    for (int ks = 0; ks < 2; ++ks) {
        const float* wp = Wa + (size_t)(w * 16 + lr) * 64 + ks * 32 + lk * 8;
        waf[ks] = cvt8(*(const float4*)wp, *(const float4*)(wp + 4));
    }
    const float4 baq = *(const float4*)(ba + w * 16 + lk * 4);

    if (w < 2) {
        const float4* xrow = (const float4*)(x + ((size_t)(b * 512 + l0 + w)) * 768);
        float4 xv[3];
        float s1 = 0.f, s2 = 0.f;
        #pragma unroll
        for (int e4 = 0; e4 < 3; ++e4) {
            float4 v = xrow[lane + 64 * e4];
            xv[e4] = v;
            s1 += v.x + v.y + v.z + v.w;
            s2 += v.x * v.x + v.y * v.y + v.z * v.z + v.w * v.w;
        }
        #pragma unroll
        for (int off = 32; off > 0; off >>= 1) {
            s1 += __shfl_xor(s1, off);
            s2 += __shfl_xor(s2, off);
        }
        float mu   = s1 * (1.0f / 768.0f);
        float var  = s2 * (1.0f / 768.0f) - mu * mu;
        float rstd = rsqrtf(var + 1e-6f);
        #pragma unroll
        for (int e4 = 0; e4 < 3; ++e4) {
            float4 lw = ((const float4*)ln_w)[lane + 64 * e4];
            float4 lb = ((const float4*)ln_b)[lane + 64 * e4];
            half4 h4;
            h4[0] = (_Float16)((xv[e4].x - mu) * rstd * lw.x + lb.x);
            h4[1] = (_Float16)((xv[e4].y - mu) * rstd * lw.y + lb.y);
            h4[2] = (_Float16)((xv[e4].z - mu) * rstd * lw.z + lb.z);
            h4[3] = (_Float16)((xv[e4].w - mu) * rstd * lw.w + lb.w);
            *(half4*)&hs16[(w * 3 + e4) * 280 + 4 * lane] = h4;
        }
    }
    __syncthreads();

    {
        f32x4 acc[4] = {};
        #pragma unroll
        for (int ks = 0; ks < 8; ++ks) {
            half8 af = *(const half8*)&hs16[lr * 280 + ks * 32 + lk * 8];
            #pragma unroll
            for (int n = 0; n < 4; ++n) {
                half8 bf = *(const half8*)(W1H + (((size_t)((w * 4 + n) * 8 + ks) * 64) + lane) * 8);
                acc[n] = MFMA_F16(af, bf, acc[n]);
            }
        }
        #pragma unroll
        for (int n = 0; n < 4; ++n) {
            int j = (w * 4 + n) * 16 + lr;
            float bb = b1[j];
            #pragma unroll
            for (int jj = 0; jj < 4; ++jj) {
                int m = lk * 4 + jj;
                if (m < 6) {
                    int r = (m >= 3) ? 1 : 0, k = m - r * 3;
                    ts2[r][k * 256 + j] = acc[n][jj] + bb;
                }
            }
        }
    }
    __syncthreads();

    {
        const int c = tid >> 3, i = tid & 7;
        #pragma unroll
        for (int r = 0; r < 2; ++r) {
            float ti0 = ts2[r][c * 8 + i], ti1 = ts2[r][256 + c * 8 + i], ti2 = ts2[r][512 + c * 8 + i];
            half8 h8;
            #pragma unroll
            for (int j = 0; j < 8; j++) {
                float m = (ti0 * ts2[r][c * 8 + j] + ti1 * ts2[r][256 + c * 8 + j]
                         + ti2 * ts2[r][512 + c * 8 + j]) * (1.0f / 3.0f);
                mos2[r][c * 68 + i * 8 + j] = m;
                h8[j] = (_Float16)m;
            }
            size_t mobase = ((size_t)(b * 32 + c) * 512 + (l0 + r)) * 64 + i * 8;
            *(half8*)(mo_g + mobase) = h8;
        }
    }
    __syncthreads();

    #pragma unroll
    for (int nt2 = 0; nt2 < 4; ++nt2) {
        const int r = nt2 >> 1, ch = nt2 & 1;
        f32x4 acc = { baq.x, baq.y, baq.z, baq.w };
        #pragma unroll
        for (int ks = 0; ks < 2; ++ks) {
            const float* mp = &mos2[r][(ch * 16 + lr) * 68 + ks * 32 + lk * 8];
            half8 mof = cvt8(*(const float4*)mp, *(const float4*)(mp + 4));
            acc = MFMA_F16(waf[ks], mof, acc);
        }
        half4 o;
        #pragma unroll
        for (int j = 0; j < 4; ++j) {
            float g = 0.5f * acc[j] * (1.0f + erff(acc[j] * 0.70710678118654752f));
            o[j] = (_Float16)g;
        }
        *(half4*)(mt_g + ((size_t)(b * 32 + ch * 16 + lr) * 512 + (l0 + r)) * 64 + w * 16 + lk * 4) = o;
    }
}

// k2: per (32 l x 32 m) tile (512 blocks):
//   phase A: raw[pair][c] = MO[c,l,:].MT[c,m,:], pair = l_loc*32+m_loc -> f16 LDS (pad 40, XOR)
//   phase B: D[p][m] = W2 . raw per l-row; in-place sc (wave's dead raw region, 20.5KB >= 16KB)
//            -> 16 x 1KB-contiguous NT f32x4 stores (16KB contiguous per l-row)
__global__ __launch_bounds__(256, 2) void k2_mfma32(
    const _Float16* __restrict__ mo, const _Float16* __restrict__ mt,
    const float* __restrict__ W2, const float* __restrict__ b2,
    float* __restrict__ out)
{
    __shared__ _Float16 raw16[1024 * 40];   // 80 KB

    const int tid  = threadIdx.x;
    const int w    = tid >> 6;
    const int lane = tid & 63;
    const int lr   = lane & 15;
    const int lk   = lane >> 4;

    // bijective XCD swizzle (nwg=512, 512%8==0)
    const int flat = blockIdx.x;
    const int nf   = (flat & 7) * 64 + (flat >> 3);
    const int m0   = (nf & 15) << 5;        // 16 m-tiles of 32
    const int l0   = ((nf >> 4) & 15) << 5; // 16 l-tiles of 32
    const int b    = nf >> 8;

    // ---- phase A: wave w computes c in [8w, 8w+8), all 1024 pairs ----
    #pragma unroll
    for (int cp = 0; cp < 4; ++cp) {
        const int c0 = w * 8 + cp * 2;
        f32x4 acc[2][2][2] = {};   // [ci][rh][mh]
        #pragma unroll
        for (int ci = 0; ci < 2; ++ci) {
            const int c = c0 + ci;
            const _Float16* mo_c = mo + (((size_t)(b * 32 + c) * 512) + l0) * 64;
            const _Float16* mt_c = mt + (((size_t)(b * 32 + c) * 512) + m0) * 64;
            #pragma unroll
            for (int ks = 0; ks < 2; ++ks) {
                half8 bfr0 = *(const half8*)(mt_c + (size_t)lr * 64 + ks * 32 + lk * 8);
                half8 bfr1 = *(const half8*)(mt_c + (size_t)(16 + lr) * 64 + ks * 32 + lk * 8);
                #pragma unroll
                for (int rh = 0; rh < 2; ++rh) {
                    half8 af = *(const half8*)(mo_c + (size_t)(rh * 16 + lr) * 64 + ks * 32 + lk * 8);
                    acc[ci][rh][0] = MFMA_F16(af, bfr0, acc[ci][rh][0]);
                    acc[ci][rh][1] = MFMA_F16(af, bfr1, acc[ci][rh][1]);
                }
            }
        }
        // park raw: D row(l_loc)=rh*16+lk*4+j, col(m_loc)=mh*16+lr
        #pragma unroll
        for (int rh = 0; rh < 2; ++rh)
        #pragma unroll
        for (int mh = 0; mh < 2; ++mh)
        #pragma unroll
        for (int j = 0; j < 4; ++j) {
            int pair = (rh * 16 + lk * 4 + j) * 32 + mh * 16 + lr;
            int sw   = (((pair >> 3) & 1) << 3) | (((pair >> 7) & 1) << 4);
            *(unsigned*)&raw16[pair * 40 + (c0 ^ sw)] = pack2f16(acc[0][rh][mh][j], acc[1][rh][mh][j]);
        }
    }

    // W2 fragments (A-op: row p = c8*16+lr, k-slice c = lk*8) + bias quads
    half8 wfrag[8]; float4 b2q[8];
    #pragma unroll
    for (int c8 = 0; c8 < 8; ++c8) {
        const float* wp = W2 + (size_t)(c8 * 16 + lr) * 32 + lk * 8;
        wfrag[c8] = cvt8(*(const float4*)wp, *(const float4*)(wp + 4));
        b2q[c8]   = *(const float4*)(b2 + c8 * 16 + lk * 4);
    }
    __syncthreads();

    // ---- phase B: wave w owns l-rows [8w,8w+8) == raw pairs [256w, 256w+256) ----
    // Pre-read ALL 16 a-frags (8 rows x 2 m-halves, 64 VGPR) -> wave's raw region is dead,
    // reuse as 16 KB sc scratch (region is 20,480 B).
    half8 afr[8][2];
    #pragma unroll
    for (int i = 0; i < 8; ++i)
    #pragma unroll
    for (int mh = 0; mh < 2; ++mh) {
        int pr = (w * 8 + i) * 32 + mh * 16 + lr;
        int sw = (((pr >> 3) & 1) << 3) | (((pr >> 7) & 1) << 4);
        afr[i][mh] = *(const half8*)&raw16[pr * 40 + ((lk * 8) ^ sw)];
    }
    float* scw = (float*)&raw16[(size_t)w * 256 * 40];

    #pragma unroll
    for (int i = 0; i < 8; ++i) {
        const int r = w * 8 + i;
        // compute D[p][m] for 32 m x 128 p; park in m-XOR-swizzled sc
        #pragma unroll
        for (int mh = 0; mh < 2; ++mh) {
            const int m = mh * 16 + lr;
            #pragma unroll
            for (int c8 = 0; c8 < 8; ++c8) {
                f32x4 d = { b2q[c8].x, b2q[c8].y, b2q[c8].z, b2q[c8].w };
                d = MFMA_F16(wfrag[c8], afr[i][mh], d);   // lane: p = c8*16+lk*4+j, m
                int chunk = (c8 * 4 + lk) ^ m;            // 5-bit chunk swizzle
                *(f32x4*)&scw[m * 128 + chunk * 4] = d;
            }
        }
        // store 16 KB contiguous for this l-row: 16 x 1KB NT f32x4
        float* ob = out + (((size_t)(b * 512 + l0 + r)) * 512 + m0) * 128;
        #pragma unroll
        for (int s = 0; s < 16; ++s) {
            int flatq = s * 256 + lane * 4;      // f32 index in 32x128 tile
            int m = flatq >> 7;
            int cpos = (flatq >> 2) & 31;
            f32x4 v = *(const f32x4*)&scw[m * 128 + ((cpos ^ m) * 4)];
            __builtin_nontemporal_store(v, (f32x4*)(ob + flatq));
        }
    }
}

extern "C" void kernel_launch(void* const* d_in, const int* in_sizes, int n_in,
                              void* d_out, int out_size, void* d_ws, size_t ws_size,
                              hipStream_t stream) {
    const float* x    = (const float*)d_in[0];
    const float* ln_w = (const float*)d_in[1];
    const float* ln_b = (const float*)d_in[2];
    const float* W1   = (const float*)d_in[3];
    const float* b1   = (const float*)d_in[4];
    const float* Wa   = (const float*)d_in[5];
    const float* ba   = (const float*)d_in[6];
    const float* W2   = (const float*)d_in[7];
    const float* b2   = (const float*)d_in[8];
    float* out = (float*)d_out;

    _Float16* mo  = (_Float16*)d_ws;                     // [2,32,512,64] f16 = 4 MB
    _Float16* mt  = mo + (size_t)2 * 32 * 512 * 64;      // [2,32,512,64] f16 = 4 MB
    _Float16* W1H = mt + (size_t)2 * 32 * 512 * 64;      // 128 KB packed f16 W1

    k0_pack<<<32, 256, 0, stream>>>(W1, W1H);
    k1_rowstage2<<<512, 256, 0, stream>>>(x, ln_w, ln_b, W1H, b1, Wa, ba, mo, mt);
    k2_mfma32<<<512, 256, 0, stream>>>(mo, mt, W2, b2, out);
}

// Round 15
// 80.684 us; speedup vs baseline: 1.0067x; 1.0067x over previous
//
#include <hip/hip_runtime.h>
#include <math.h>

// B=2, L=512, C=768, C/3=256, pairDim=128
// ws: mo [2,32,512,64] f16 (4MB) | mt same (4MB) | W1H f16 (128KB) | tg f32 [1024][768] (3MB)
// k1 split: k1a = LN + GEMM1 -> tg (global f32, exact); k1b = outer + GEMM2 (1024 blocks,
// ~10KB LDS, high occupancy). Attacks measured latency-boundedness of the monolithic chain.

typedef __attribute__((ext_vector_type(8))) _Float16 half8;
typedef __attribute__((ext_vector_type(4))) _Float16 half4;
typedef __attribute__((ext_vector_type(4))) float f32x4;

#define MFMA_F16(a,b,c) __builtin_amdgcn_mfma_f32_16x16x32_f16((a),(b),(c),0,0,0)

static __device__ inline unsigned pack2f16(float a, float b) {
    _Float16 ha = (_Float16)a, hb = (_Float16)b;
    unsigned short ua = __builtin_bit_cast(unsigned short, ha);
    unsigned short ub = __builtin_bit_cast(unsigned short, hb);
    return (unsigned)ua | ((unsigned)ub << 16);
}

static __device__ inline half8 cvt8(float4 u, float4 v) {
    half8 h;
    h[0] = (_Float16)u.x; h[1] = (_Float16)u.y; h[2] = (_Float16)u.z; h[3] = (_Float16)u.w;
    h[4] = (_Float16)v.x; h[5] = (_Float16)v.y; h[6] = (_Float16)v.z; h[7] = (_Float16)v.w;
    return h;
}

// k0: W1 [256 j][256 i] f32 -> W1H f16 B-frag order [nt][ks][lane][8]
__global__ __launch_bounds__(256) void k0_pack(const float* __restrict__ W1, _Float16* __restrict__ W1H)
{
    int flat8 = blockIdx.x * 256 + threadIdx.x;   // 0..8191 (8-elem chunks)
    int j  = flat8 >> 5, i8 = flat8 & 31;
    int nt = j >> 4, lr = j & 15, ks = i8 >> 2, lk = i8 & 3;
    const float4* src = (const float4*)(W1 + (size_t)j * 256 + (size_t)i8 * 8);
    half8 h = cvt8(src[0], src[1]);
    *(half8*)(W1H + (((size_t)(nt * 8 + ks) * 64) + lk * 16 + lr) * 8) = h;
}

// k1a: 512 blocks x 2 rows: LN + GEMM1(MFMA) -> tg f32 [row][768]
__global__ __launch_bounds__(256) void k1a_ln_gemm1(
    const float* __restrict__ x, const float* __restrict__ ln_w, const float* __restrict__ ln_b,
    const _Float16* __restrict__ W1H, const float* __restrict__ b1,
    float* __restrict__ tg)
{
    const int blk = blockIdx.x;
    const int b   = blk >> 8;
    const int l0  = (blk & 255) << 1;    // 2 rows
    const int tid = threadIdx.x;
    const int w   = tid >> 6;
    const int lane = tid & 63;
    const int lr  = lane & 15;
    const int lk  = lane >> 4;

    __shared__ _Float16 hs16[16 * 280];  // A rows m=r*3+k (6 used; rest garbage, D-rows unread)
    __shared__ float ts2[2][776];

    // ---- LN: waves 0,1 own rows l0+w ----
    if (w < 2) {
        const float4* xrow = (const float4*)(x + ((size_t)(b * 512 + l0 + w)) * 768);
        float4 xv[3];
        float s1 = 0.f, s2 = 0.f;
        #pragma unroll
        for (int e4 = 0; e4 < 3; ++e4) {
            float4 v = xrow[lane + 64 * e4];
            xv[e4] = v;
            s1 += v.x + v.y + v.z + v.w;
            s2 += v.x * v.x + v.y * v.y + v.z * v.z + v.w * v.w;
        }
        #pragma unroll
        for (int off = 32; off > 0; off >>= 1) {
            s1 += __shfl_xor(s1, off);
            s2 += __shfl_xor(s2, off);
        }
        float mu   = s1 * (1.0f / 768.0f);
        float var  = s2 * (1.0f / 768.0f) - mu * mu;
        float rstd = rsqrtf(var + 1e-6f);
        #pragma unroll
        for (int e4 = 0; e4 < 3; ++e4) {
            float4 lw = ((const float4*)ln_w)[lane + 64 * e4];
            float4 lb = ((const float4*)ln_b)[lane + 64 * e4];
            half4 h4;
            h4[0] = (_Float16)((xv[e4].x - mu) * rstd * lw.x + lb.x);
            h4[1] = (_Float16)((xv[e4].y - mu) * rstd * lw.y + lb.y);
            h4[2] = (_Float16)((xv[e4].z - mu) * rstd * lw.z + lb.z);
            h4[3] = (_Float16)((xv[e4].w - mu) * rstd * lw.w + lb.w);
            *(half4*)&hs16[(w * 3 + e4) * 280 + 4 * lane] = h4;
        }
    }
    __syncthreads();

    // ---- GEMM1 (MFMA): A rows m=r*3+k < 6 ----
    {
        f32x4 acc[4] = {};
        #pragma unroll
        for (int ks = 0; ks < 8; ++ks) {
            half8 af = *(const half8*)&hs16[lr * 280 + ks * 32 + lk * 8];
            #pragma unroll
            for (int n = 0; n < 4; ++n) {
                half8 bf = *(const half8*)(W1H + (((size_t)((w * 4 + n) * 8 + ks) * 64) + lane) * 8);
                acc[n] = MFMA_F16(af, bf, acc[n]);
            }
        }
        #pragma unroll
        for (int n = 0; n < 4; ++n) {
            int j = (w * 4 + n) * 16 + lr;
            float bb = b1[j];
            #pragma unroll
            for (int jj = 0; jj < 4; ++jj) {
                int m = lk * 4 + jj;
                if (m < 6) {
                    int r = (m >= 3) ? 1 : 0, k = m - r * 3;
                    ts2[r][k * 256 + j] = acc[n][jj] + bb;
                }
            }
        }
    }
    __syncthreads();

    // ---- writeback: ts2 -> tg (coalesced float4) ----
    #pragma unroll
    for (int rep = 0; rep < 2; ++rep) {
        int idx4 = tid + rep * 256;
        if (idx4 < 384) {
            int r = idx4 / 192, o4 = idx4 - r * 192;
            float4 v = *(const float4*)&ts2[r][o4 * 4];
            *(float4*)(tg + ((size_t)(b * 512 + l0 + r)) * 768 + o4 * 4) = v;
        }
    }
}

// k1b: 1024 blocks x 1 row: outer product + GEMM2 (high occupancy, ~10KB LDS)
__global__ __launch_bounds__(256) void k1b_outer_gemm2(
    const float* __restrict__ tg, const float* __restrict__ Wa, const float* __restrict__ ba,
    _Float16* __restrict__ mo_g, _Float16* __restrict__ mt_g)
{
    const int blk = blockIdx.x;
    const int b   = blk >> 9;
    const int l   = blk & 511;
    const int tid = threadIdx.x;
    const int w   = tid >> 6;
    const int lane = tid & 63;
    const int lr  = lane & 15;
    const int lk  = lane >> 4;

    __shared__ float ts[776];        // 768 used
    __shared__ float mos[32 * 68];

    // Wa fragments + bias (L2-hot)
    half8 waf[2];
    #pragma unroll
    for (int ks = 0; ks < 2; ++ks) {
        const float* wp = Wa + (size_t)(w * 16 + lr) * 64 + ks * 32 + lk * 8;
        waf[ks] = cvt8(*(const float4*)wp, *(const float4*)(wp + 4));
    }
    const float4 baq = *(const float4*)(ba + w * 16 + lk * 4);

    // stage t row (f32, exact)
    if (tid < 192) {
        float4 v = ((const float4*)(tg + (size_t)(b * 512 + l) * 768))[tid];
        *(float4*)&ts[tid * 4] = v;
    }
    __syncthreads();

    // outer product -> mos + mo_g (f16)
    {
        const int c = tid >> 3, i = tid & 7;
        float ti0 = ts[c * 8 + i], ti1 = ts[256 + c * 8 + i], ti2 = ts[512 + c * 8 + i];
        half8 h8;
        #pragma unroll
        for (int j = 0; j < 8; j++) {
            float m = (ti0 * ts[c * 8 + j] + ti1 * ts[256 + c * 8 + j]
                     + ti2 * ts[512 + c * 8 + j]) * (1.0f / 3.0f);
            mos[c * 68 + i * 8 + j] = m;
            h8[j] = (_Float16)m;
        }
        size_t mobase = ((size_t)(b * 32 + c) * 512 + l) * 64 + i * 8;
        *(half8*)(mo_g + mobase) = h8;
    }
    __syncthreads();

    // GEMM2 (MFMA): mt[d][c] = gelu(Wa . mo + ba)
    #pragma unroll
    for (int ch = 0; ch < 2; ++ch) {
        f32x4 acc = { baq.x, baq.y, baq.z, baq.w };
        #pragma unroll
        for (int ks = 0; ks < 2; ++ks) {
            const float* mp = &mos[(ch * 16 + lr) * 68 + ks * 32 + lk * 8];
            half8 mof = cvt8(*(const float4*)mp, *(const float4*)(mp + 4));
            acc = MFMA_F16(waf[ks], mof, acc);
        }
        half4 o;
        #pragma unroll
        for (int j = 0; j < 4; ++j) {
            float g = 0.5f * acc[j] * (1.0f + erff(acc[j] * 0.70710678118654752f));
            o[j] = (_Float16)g;
        }
        *(half4*)(mt_g + ((size_t)(b * 32 + ch * 16 + lr) * 512 + l) * 64 + w * 16 + lk * 4) = o;
    }
}

// k2 (R4 verbatim — proven local optimum): per (32 l x 16 m) tile:
//   phase A (MFMA): raw[pair][c] -> f16 LDS (pad 40, XOR-swizzled)
//   phase B (MFMA): D[p][pair] = W2 . raw; per-wave LDS transpose ->
//                   8 x 1KB-contiguous nontemporal f32x4 stores per l-row
__global__ __launch_bounds__(256, 2) void k2_mfma(
    const _Float16* __restrict__ mo, const _Float16* __restrict__ mt,
    const float* __restrict__ W2, const float* __restrict__ b2,
    float* __restrict__ out)
{
    __shared__ _Float16 raw16[512 * 40];   // 40 KB
    __shared__ float sc[4][2048];          // 32 KB

    const int tid  = threadIdx.x;
    const int w    = tid >> 6;
    const int lane = tid & 63;
    const int lr   = lane & 15;
    const int lk   = lane >> 4;

    const int flat = blockIdx.x;
    const int nf   = (flat & 7) * 128 + (flat >> 3);
    const int m0   = (nf & 31) << 4;
    const int l0   = ((nf >> 5) & 15) << 5;
    const int b    = nf >> 9;

    #pragma unroll
    for (int cp = 0; cp < 4; ++cp) {
        const int c0 = w * 8 + cp * 2;
        f32x4 acc[2][2] = {};
        #pragma unroll
        for (int ci = 0; ci < 2; ++ci) {
            const int c = c0 + ci;
            const _Float16* mo_c = mo + (((size_t)(b * 32 + c) * 512) + l0) * 64;
            const _Float16* mt_c = mt + (((size_t)(b * 32 + c) * 512) + m0) * 64;
            #pragma unroll
            for (int ks = 0; ks < 2; ++ks) {
                half8 bfrag = *(const half8*)(mt_c + (size_t)lr * 64 + ks * 32 + lk * 8);
                #pragma unroll
                for (int rh = 0; rh < 2; ++rh) {
                    half8 afrag = *(const half8*)(mo_c + (size_t)(rh * 16 + lr) * 64 + ks * 32 + lk * 8);
                    acc[ci][rh] = MFMA_F16(afrag, bfrag, acc[ci][rh]);
                }
            }
        }
        #pragma unroll
        for (int rh = 0; rh < 2; ++rh) {
            #pragma unroll
            for (int j = 0; j < 4; ++j) {
                int pair = (rh * 16 + lk * 4 + j) * 16 + lr;
                int sw   = (((pair >> 3) & 1) << 3) | (((pair >> 6) & 1) << 4);
                *(unsigned*)&raw16[pair * 40 + (c0 ^ sw)] = pack2f16(acc[0][rh][j], acc[1][rh][j]);
            }
        }
    }

    half8 wfrag[8]; float4 b2q[8];
    #pragma unroll
    for (int c8 = 0; c8 < 8; ++c8) {
        const float* wp = W2 + (size_t)(c8 * 16 + lr) * 32 + lk * 8;
        wfrag[c8] = cvt8(*(const float4*)wp, *(const float4*)(wp + 4));
        b2q[c8]   = *(const float4*)(b2 + c8 * 16 + lk * 4);
    }
    __syncthreads();

    for (int i = 0; i < 8; ++i) {
        const int r  = w * 8 + i;
        const int pr = r * 16 + lr;
        const int swr = (((pr >> 3) & 1) << 3) | (((pr >> 6) & 1) << 4);
        half8 a = *(const half8*)&raw16[pr * 40 + ((lk * 8) ^ swr)];

        #pragma unroll
        for (int c8 = 0; c8 < 8; ++c8) {
            f32x4 d = { b2q[c8].x, b2q[c8].y, b2q[c8].z, b2q[c8].w };
            d = MFMA_F16(wfrag[c8], a, d);
            int chunk = (c8 * 4 + lk) ^ lr;
            *(f32x4*)&sc[w][lr * 128 + chunk * 4] = d;
        }
        float* ob = out + (((size_t)(b * 512 + l0 + r)) * 512 + m0) * 128;
        #pragma unroll
        for (int s = 0; s < 8; ++s) {
            int mm = s * 2 + (lane >> 5);
            int cp = (lane & 31) ^ mm;
            f32x4 v = *(const f32x4*)&sc[w][mm * 128 + cp * 4];
            __builtin_nontemporal_store(v, (f32x4*)(ob + s * 256 + lane * 4));
        }
    }
}

extern "C" void kernel_launch(void* const* d_in, const int* in_sizes, int n_in,
                              void* d_out, int out_size, void* d_ws, size_t ws_size,
                              hipStream_t stream) {
    const float* x    = (const float*)d_in[0];
    const float* ln_w = (const float*)d_in[1];
    const float* ln_b = (const float*)d_in[2];
    const float* W1   = (const float*)d_in[3];
    const float* b1   = (const float*)d_in[4];
    const float* Wa   = (const float*)d_in[5];
    const float* ba   = (const float*)d_in[6];
    const float* W2   = (const float*)d_in[7];
    const float* b2   = (const float*)d_in[8];
    float* out = (float*)d_out;

    _Float16* mo  = (_Float16*)d_ws;                     // 4 MB
    _Float16* mt  = mo + (size_t)2 * 32 * 512 * 64;      // 4 MB
    _Float16* W1H = mt + (size_t)2 * 32 * 512 * 64;      // 128 KB
    float* tg     = (float*)(W1H + 65536);               // 3 MB f32 [1024][768]

    k0_pack<<<32, 256, 0, stream>>>(W1, W1H);
    k1a_ln_gemm1<<<512, 256, 0, stream>>>(x, ln_w, ln_b, W1H, b1, tg);
    k1b_outer_gemm2<<<1024, 256, 0, stream>>>(tg, Wa, ba, mo, mt);
    k2_mfma<<<1024, 256, 0, stream>>>(mo, mt, W2, b2, out);
}

// Round 16
// 75.171 us; speedup vs baseline: 1.0806x; 1.0733x over previous
//
#include <hip/hip_runtime.h>
#include <math.h>

// B=2, L=512, C=768, C/3=256, pairDim=128
// ws: mo [2,32,512,64] f16 (4 MB) | mt same (4 MB) | W1H f16 frag-packed 128 KB
// R16 = R13 (best, 76.3us) + two k1 micro-fixes:
//   (1) W1H B-frags prefetched at kernel entry (T14 issue-early) — hides L2 latency under LN
//   (2) exact-erf gelu -> tanh-form gelu (~10 VALU ops vs ~30+ for erff)

typedef __attribute__((ext_vector_type(8))) _Float16 half8;
typedef __attribute__((ext_vector_type(4))) _Float16 half4;
typedef __attribute__((ext_vector_type(4))) float f32x4;

#define MFMA_F16(a,b,c) __builtin_amdgcn_mfma_f32_16x16x32_f16((a),(b),(c),0,0,0)

static __device__ inline unsigned pack2f16(float a, float b) {
    _Float16 ha = (_Float16)a, hb = (_Float16)b;
    unsigned short ua = __builtin_bit_cast(unsigned short, ha);
    unsigned short ub = __builtin_bit_cast(unsigned short, hb);
    return (unsigned)ua | ((unsigned)ub << 16);
}

static __device__ inline half8 cvt8(float4 u, float4 v) {
    half8 h;
    h[0] = (_Float16)u.x; h[1] = (_Float16)u.y; h[2] = (_Float16)u.z; h[3] = (_Float16)u.w;
    h[4] = (_Float16)v.x; h[5] = (_Float16)v.y; h[6] = (_Float16)v.z; h[7] = (_Float16)v.w;
    return h;
}

// tanh-form gelu: max dev from exact-erf gelu ~1e-3 (same order as f16 rounding of mt)
static __device__ inline float gelu_fast(float v) {
    float u  = 0.7978845608028654f * (v + 0.044715f * v * v * v);
    float t  = __expf(-2.0f * fabsf(u));
    float th = 1.0f - 2.0f * t / (1.0f + t);     // tanh(|u|)
    th = copysignf(th, u);
    return 0.5f * v * (1.0f + th);
}

// k0: W1 [256 j][256 i] f32 -> W1H f16 B-frag order [nt][ks][lane][8]
__global__ __launch_bounds__(256) void k0_pack(const float* __restrict__ W1, _Float16* __restrict__ W1H)
{
    int flat8 = blockIdx.x * 256 + threadIdx.x;   // 0..8191 (8-elem chunks)
    int j  = flat8 >> 5, i8 = flat8 & 31;
    int nt = j >> 4, lr = j & 15, ks = i8 >> 2, lk = i8 & 3;
    const float4* src = (const float4*)(W1 + (size_t)j * 256 + (size_t)i8 * 8);
    half8 h = cvt8(src[0], src[1]);
    *(half8*)(W1H + (((size_t)(nt * 8 + ks) * 64) + lk * 16 + lr) * 8) = h;
}

// k1: 512 blocks x 256 threads; block handles rows l0, l0+1 of batch b.
__global__ __launch_bounds__(256, 2) void k1_rowstage2(
    const float* __restrict__ x, const float* __restrict__ ln_w, const float* __restrict__ ln_b,
    const _Float16* __restrict__ W1H, const float* __restrict__ b1,
    const float* __restrict__ Wa, const float* __restrict__ ba,
    _Float16* __restrict__ mo_g, _Float16* __restrict__ mt_g)
{
    const int blk = blockIdx.x;
    const int b   = blk >> 8;
    const int l0  = (blk & 255) << 1;    // 2 rows
    const int tid = threadIdx.x;
    const int w   = tid >> 6;
    const int lane = tid & 63;
    const int lr  = lane & 15;
    const int lk  = lane >> 4;

    __shared__ _Float16 hs16[16 * 280];  // A rows m=r*3+k (6 used; 6-15 garbage, D-rows unread)
    __shared__ float ts2[2][776];
    __shared__ float mos2[2][2176];

    // ---- PREFETCH: all 32 GEMM1 B-frags into registers at entry (L2-latency hides under LN)
    half8 bfr[32];
    #pragma unroll
    for (int ks = 0; ks < 8; ++ks)
        #pragma unroll
        for (int n = 0; n < 4; ++n)
            bfr[ks * 4 + n] = *(const half8*)(W1H + (((size_t)((w * 4 + n) * 8 + ks) * 64) + lane) * 8);

    // Wa fragments for GEMM2 + bias
    half8 waf[2];
    #pragma unroll
    for (int ks = 0; ks < 2; ++ks) {
        const float* wp = Wa + (size_t)(w * 16 + lr) * 64 + ks * 32 + lk * 8;
        waf[ks] = cvt8(*(const float4*)wp, *(const float4*)(wp + 4));
    }
    const float4 baq = *(const float4*)(ba + w * 16 + lk * 4);

    // ---- LN: waves 0,1 own rows l0+w; wave-local butterfly reduce ----
    if (w < 2) {
        const float4* xrow = (const float4*)(x + ((size_t)(b * 512 + l0 + w)) * 768);
        float4 xv[3];
        float s1 = 0.f, s2 = 0.f;
        #pragma unroll
        for (int e4 = 0; e4 < 3; ++e4) {
            float4 v = xrow[lane + 64 * e4];
            xv[e4] = v;
            s1 += v.x + v.y + v.z + v.w;
            s2 += v.x * v.x + v.y * v.y + v.z * v.z + v.w * v.w;
        }
        #pragma unroll
        for (int off = 32; off > 0; off >>= 1) {
            s1 += __shfl_xor(s1, off);
            s2 += __shfl_xor(s2, off);
        }
        float mu   = s1 * (1.0f / 768.0f);
        float var  = s2 * (1.0f / 768.0f) - mu * mu;
        float rstd = rsqrtf(var + 1e-6f);
        #pragma unroll
        for (int e4 = 0; e4 < 3; ++e4) {
            float4 lw = ((const float4*)ln_w)[lane + 64 * e4];
            float4 lb = ((const float4*)ln_b)[lane + 64 * e4];
            half4 h4;
            h4[0] = (_Float16)((xv[e4].x - mu) * rstd * lw.x + lb.x);
            h4[1] = (_Float16)((xv[e4].y - mu) * rstd * lw.y + lb.y);
            h4[2] = (_Float16)((xv[e4].z - mu) * rstd * lw.z + lb.z);
            h4[3] = (_Float16)((xv[e4].w - mu) * rstd * lw.w + lb.w);
            *(half4*)&hs16[(w * 3 + e4) * 280 + 4 * lane] = h4;
        }
    }
    __syncthreads();

    // ---- GEMM1 (MFMA): t[r][k][j] = h[r][k] . W1[j,:] + b1[j]; A rows m=r*3+k < 6 ----
    {
        f32x4 acc[4] = {};
        #pragma unroll
        for (int ks = 0; ks < 8; ++ks) {
            half8 af = *(const half8*)&hs16[lr * 280 + ks * 32 + lk * 8];
            #pragma unroll
            for (int n = 0; n < 4; ++n)
                acc[n] = MFMA_F16(af, bfr[ks * 4 + n], acc[n]);
        }
        #pragma unroll
        for (int n = 0; n < 4; ++n) {
            int j = (w * 4 + n) * 16 + lr;
            float bb = b1[j];
            #pragma unroll
            for (int jj = 0; jj < 4; ++jj) {
                int m = lk * 4 + jj;
                if (m < 6) {
                    int r = (m >= 3) ? 1 : 0, k = m - r * 3;
                    ts2[r][k * 256 + j] = acc[n][jj] + bb;
                }
            }
        }
    }
    __syncthreads();

    // ---- outer product -> mos2 + mo_g (f16), per row ----
    {
        const int c = tid >> 3, i = tid & 7;
        #pragma unroll
        for (int r = 0; r < 2; ++r) {
            float ti0 = ts2[r][c * 8 + i], ti1 = ts2[r][256 + c * 8 + i], ti2 = ts2[r][512 + c * 8 + i];
            half8 h8;
            #pragma unroll
            for (int j = 0; j < 8; j++) {
                float m = (ti0 * ts2[r][c * 8 + j] + ti1 * ts2[r][256 + c * 8 + j]
                         + ti2 * ts2[r][512 + c * 8 + j]) * (1.0f / 3.0f);
                mos2[r][c * 68 + i * 8 + j] = m;
                h8[j] = (_Float16)m;
            }
            size_t mobase = ((size_t)(b * 32 + c) * 512 + (l0 + r)) * 64 + i * 8;
            *(half8*)(mo_g + mobase) = h8;
        }
    }
    __syncthreads();

    // ---- GEMM2 (MFMA): mt[d][c] = gelu(Wa . mo_r + ba); 4 n-tiles = 2 rows x 2 c-halves ----
    #pragma unroll
    for (int nt2 = 0; nt2 < 4; ++nt2) {
        const int r = nt2 >> 1, ch = nt2 & 1;
        f32x4 acc = { baq.x, baq.y, baq.z, baq.w };
        #pragma unroll
        for (int ks = 0; ks < 2; ++ks) {
            const float* mp = &mos2[r][(ch * 16 + lr) * 68 + ks * 32 + lk * 8];
            half8 mof = cvt8(*(const float4*)mp, *(const float4*)(mp + 4));
            acc = MFMA_F16(waf[ks], mof, acc);
        }
        half4 o;
        #pragma unroll
        for (int j = 0; j < 4; ++j)
            o[j] = (_Float16)gelu_fast(acc[j]);
        *(half4*)(mt_g + ((size_t)(b * 32 + ch * 16 + lr) * 512 + (l0 + r)) * 64 + w * 16 + lk * 4) = o;
    }
}

// k2 (R4 verbatim — proven local optimum): per (32 l x 16 m) tile:
//   phase A (MFMA): raw[pair][c] -> f16 LDS (pad 40, XOR-swizzled)
//   phase B (MFMA): D[p][pair] = W2 . raw; per-wave LDS transpose ->
//                   8 x 1KB-contiguous nontemporal f32x4 stores per l-row
__global__ __launch_bounds__(256, 2) void k2_mfma(
    const _Float16* __restrict__ mo, const _Float16* __restrict__ mt,
    const float* __restrict__ W2, const float* __restrict__ b2,
    float* __restrict__ out)
{
    __shared__ _Float16 raw16[512 * 40];   // 40 KB
    __shared__ float sc[4][2048];          // 32 KB

    const int tid  = threadIdx.x;
    const int w    = tid >> 6;
    const int lane = tid & 63;
    const int lr   = lane & 15;
    const int lk   = lane >> 4;

    const int flat = blockIdx.x;
    const int nf   = (flat & 7) * 128 + (flat >> 3);
    const int m0   = (nf & 31) << 4;
    const int l0   = ((nf >> 5) & 15) << 5;
    const int b    = nf >> 9;

    #pragma unroll
    for (int cp = 0; cp < 4; ++cp) {
        const int c0 = w * 8 + cp * 2;
        f32x4 acc[2][2] = {};
        #pragma unroll
        for (int ci = 0; ci < 2; ++ci) {
            const int c = c0 + ci;
            const _Float16* mo_c = mo + (((size_t)(b * 32 + c) * 512) + l0) * 64;
            const _Float16* mt_c = mt + (((size_t)(b * 32 + c) * 512) + m0) * 64;
            #pragma unroll
            for (int ks = 0; ks < 2; ++ks) {
                half8 bfrag = *(const half8*)(mt_c + (size_t)lr * 64 + ks * 32 + lk * 8);
                #pragma unroll
                for (int rh = 0; rh < 2; ++rh) {
                    half8 afrag = *(const half8*)(mo_c + (size_t)(rh * 16 + lr) * 64 + ks * 32 + lk * 8);
                    acc[ci][rh] = MFMA_F16(afrag, bfrag, acc[ci][rh]);
                }
            }
        }
        #pragma unroll
        for (int rh = 0; rh < 2; ++rh) {
            #pragma unroll
            for (int j = 0; j < 4; ++j) {
                int pair = (rh * 16 + lk * 4 + j) * 16 + lr;
                int sw   = (((pair >> 3) & 1) << 3) | (((pair >> 6) & 1) << 4);
                *(unsigned*)&raw16[pair * 40 + (c0 ^ sw)] = pack2f16(acc[0][rh][j], acc[1][rh][j]);
            }
        }
    }

    half8 wfrag[8]; float4 b2q[8];
    #pragma unroll
    for (int c8 = 0; c8 < 8; ++c8) {
        const float* wp = W2 + (size_t)(c8 * 16 + lr) * 32 + lk * 8;
        wfrag[c8] = cvt8(*(const float4*)wp, *(const float4*)(wp + 4));
        b2q[c8]   = *(const float4*)(b2 + c8 * 16 + lk * 4);
    }
    __syncthreads();

    for (int i = 0; i < 8; ++i) {
        const int r  = w * 8 + i;
        const int pr = r * 16 + lr;
        const int swr = (((pr >> 3) & 1) << 3) | (((pr >> 6) & 1) << 4);
        half8 a = *(const half8*)&raw16[pr * 40 + ((lk * 8) ^ swr)];

        #pragma unroll
        for (int c8 = 0; c8 < 8; ++c8) {
            f32x4 d = { b2q[c8].x, b2q[c8].y, b2q[c8].z, b2q[c8].w };
            d = MFMA_F16(wfrag[c8], a, d);
            int chunk = (c8 * 4 + lk) ^ lr;
            *(f32x4*)&sc[w][lr * 128 + chunk * 4] = d;
        }
        float* ob = out + (((size_t)(b * 512 + l0 + r)) * 512 + m0) * 128;
        #pragma unroll
        for (int s = 0; s < 8; ++s) {
            int mm = s * 2 + (lane >> 5);
            int cp = (lane & 31) ^ mm;
            f32x4 v = *(const f32x4*)&sc[w][mm * 128 + cp * 4];
            __builtin_nontemporal_store(v, (f32x4*)(ob + s * 256 + lane * 4));
        }
    }
}

extern "C" void kernel_launch(void* const* d_in, const int* in_sizes, int n_in,
                              void* d_out, int out_size, void* d_ws, size_t ws_size,
                              hipStream_t stream) {
    const float* x    = (const float*)d_in[0];
    const float* ln_w = (const float*)d_in[1];
    const float* ln_b = (const float*)d_in[2];
    const float* W1   = (const float*)d_in[3];
    const float* b1   = (const float*)d_in[4];
    const float* Wa   = (const float*)d_in[5];
    const float* ba   = (const float*)d_in[6];
    const float* W2   = (const float*)d_in[7];
    const float* b2   = (const float*)d_in[8];
    float* out = (float*)d_out;

    _Float16* mo  = (_Float16*)d_ws;                     // 4 MB
    _Float16* mt  = mo + (size_t)2 * 32 * 512 * 64;      // 4 MB
    _Float16* W1H = mt + (size_t)2 * 32 * 512 * 64;      // 128 KB

    k0_pack<<<32, 256, 0, stream>>>(W1, W1H);
    k1_rowstage2<<<512, 256, 0, stream>>>(x, ln_w, ln_b, W1H, b1, Wa, ba, mo, mt);
    k2_mfma<<<1024, 256, 0, stream>>>(mo, mt, W2, b2, out);
}

// Round 17
// 74.854 us; speedup vs baseline: 1.0851x; 1.0042x over previous
//
#include <hip/hip_runtime.h>
#include <math.h>

// B=2, L=512, C=768, C/3=256, pairDim=128
// ws: mo [2,32,512,64] f16 (4 MB) | mt same (4 MB) | W1H f16 frag-packed 128 KB
// R17 = R16 + vectorized outer-product phase (float4 LDS reads/writes, bit-identical math)

typedef __attribute__((ext_vector_type(8))) _Float16 half8;
typedef __attribute__((ext_vector_type(4))) _Float16 half4;
typedef __attribute__((ext_vector_type(4))) float f32x4;

#define MFMA_F16(a,b,c) __builtin_amdgcn_mfma_f32_16x16x32_f16((a),(b),(c),0,0,0)

static __device__ inline unsigned pack2f16(float a, float b) {
    _Float16 ha = (_Float16)a, hb = (_Float16)b;
    unsigned short ua = __builtin_bit_cast(unsigned short, ha);
    unsigned short ub = __builtin_bit_cast(unsigned short, hb);
    return (unsigned)ua | ((unsigned)ub << 16);
}

static __device__ inline half8 cvt8(float4 u, float4 v) {
    half8 h;
    h[0] = (_Float16)u.x; h[1] = (_Float16)u.y; h[2] = (_Float16)u.z; h[3] = (_Float16)u.w;
    h[4] = (_Float16)v.x; h[5] = (_Float16)v.y; h[6] = (_Float16)v.z; h[7] = (_Float16)v.w;
    return h;
}

// tanh-form gelu: max dev from exact-erf gelu ~1e-3
static __device__ inline float gelu_fast(float v) {
    float u  = 0.7978845608028654f * (v + 0.044715f * v * v * v);
    float t  = __expf(-2.0f * fabsf(u));
    float th = 1.0f - 2.0f * t / (1.0f + t);     // tanh(|u|)
    th = copysignf(th, u);
    return 0.5f * v * (1.0f + th);
}

// k0: W1 [256 j][256 i] f32 -> W1H f16 B-frag order [nt][ks][lane][8]
__global__ __launch_bounds__(256) void k0_pack(const float* __restrict__ W1, _Float16* __restrict__ W1H)
{
    int flat8 = blockIdx.x * 256 + threadIdx.x;   // 0..8191 (8-elem chunks)
    int j  = flat8 >> 5, i8 = flat8 & 31;
    int nt = j >> 4, lr = j & 15, ks = i8 >> 2, lk = i8 & 3;
    const float4* src = (const float4*)(W1 + (size_t)j * 256 + (size_t)i8 * 8);
    half8 h = cvt8(src[0], src[1]);
    *(half8*)(W1H + (((size_t)(nt * 8 + ks) * 64) + lk * 16 + lr) * 8) = h;
}

// k1: 512 blocks x 256 threads; block handles rows l0, l0+1 of batch b.
__global__ __launch_bounds__(256, 2) void k1_rowstage2(
    const float* __restrict__ x, const float* __restrict__ ln_w, const float* __restrict__ ln_b,
    const _Float16* __restrict__ W1H, const float* __restrict__ b1,
    const float* __restrict__ Wa, const float* __restrict__ ba,
    _Float16* __restrict__ mo_g, _Float16* __restrict__ mt_g)
{
    const int blk = blockIdx.x;
    const int b   = blk >> 8;
    const int l0  = (blk & 255) << 1;    // 2 rows
    const int tid = threadIdx.x;
    const int w   = tid >> 6;
    const int lane = tid & 63;
    const int lr  = lane & 15;
    const int lk  = lane >> 4;

    __shared__ _Float16 hs16[16 * 280];  // A rows m=r*3+k (6 used; 6-15 garbage, D-rows unread)
    __shared__ float ts2[2][776];
    __shared__ float mos2[2][2176];

    // ---- PREFETCH: all 32 GEMM1 B-frags into registers at entry (L2-latency hides under LN)
    half8 bfr[32];
    #pragma unroll
    for (int ks = 0; ks < 8; ++ks)
        #pragma unroll
        for (int n = 0; n < 4; ++n)
            bfr[ks * 4 + n] = *(const half8*)(W1H + (((size_t)((w * 4 + n) * 8 + ks) * 64) + lane) * 8);

    // Wa fragments for GEMM2 + bias
    half8 waf[2];
    #pragma unroll
    for (int ks = 0; ks < 2; ++ks) {
        const float* wp = Wa + (size_t)(w * 16 + lr) * 64 + ks * 32 + lk * 8;
        waf[ks] = cvt8(*(const float4*)wp, *(const float4*)(wp + 4));
    }
    const float4 baq = *(const float4*)(ba + w * 16 + lk * 4);

    // ---- LN: waves 0,1 own rows l0+w; wave-local butterfly reduce ----
    if (w < 2) {
        const float4* xrow = (const float4*)(x + ((size_t)(b * 512 + l0 + w)) * 768);
        float4 xv[3];
        float s1 = 0.f, s2 = 0.f;
        #pragma unroll
        for (int e4 = 0; e4 < 3; ++e4) {
            float4 v = xrow[lane + 64 * e4];
            xv[e4] = v;
            s1 += v.x + v.y + v.z + v.w;
            s2 += v.x * v.x + v.y * v.y + v.z * v.z + v.w * v.w;
        }
        #pragma unroll
        for (int off = 32; off > 0; off >>= 1) {
            s1 += __shfl_xor(s1, off);
            s2 += __shfl_xor(s2, off);
        }
        float mu   = s1 * (1.0f / 768.0f);
        float var  = s2 * (1.0f / 768.0f) - mu * mu;
        float rstd = rsqrtf(var + 1e-6f);
        #pragma unroll
        for (int e4 = 0; e4 < 3; ++e4) {
            float4 lw = ((const float4*)ln_w)[lane + 64 * e4];
            float4 lb = ((const float4*)ln_b)[lane + 64 * e4];
            half4 h4;
            h4[0] = (_Float16)((xv[e4].x - mu) * rstd * lw.x + lb.x);
            h4[1] = (_Float16)((xv[e4].y - mu) * rstd * lw.y + lb.y);
            h4[2] = (_Float16)((xv[e4].z - mu) * rstd * lw.z + lb.z);
            h4[3] = (_Float16)((xv[e4].w - mu) * rstd * lw.w + lb.w);
            *(half4*)&hs16[(w * 3 + e4) * 280 + 4 * lane] = h4;
        }
    }
    __syncthreads();

    // ---- GEMM1 (MFMA): t[r][k][j] = h[r][k] . W1[j,:] + b1[j]; A rows m=r*3+k < 6 ----
    {
        f32x4 acc[4] = {};
        #pragma unroll
        for (int ks = 0; ks < 8; ++ks) {
            half8 af = *(const half8*)&hs16[lr * 280 + ks * 32 + lk * 8];
            #pragma unroll
            for (int n = 0; n < 4; ++n)
                acc[n] = MFMA_F16(af, bfr[ks * 4 + n], acc[n]);
        }
        #pragma unroll
        for (int n = 0; n < 4; ++n) {
            int j = (w * 4 + n) * 16 + lr;
            float bb = b1[j];
            #pragma unroll
            for (int jj = 0; jj < 4; ++jj) {
                int m = lk * 4 + jj;
                if (m < 6) {
                    int r = (m >= 3) ? 1 : 0, k = m - r * 3;
                    ts2[r][k * 256 + j] = acc[n][jj] + bb;
                }
            }
        }
    }
    __syncthreads();

    // ---- outer product -> mos2 + mo_g (f16), per row — VECTORIZED LDS access ----
    {
        const int c = tid >> 3, i = tid & 7;
        #pragma unroll
        for (int r = 0; r < 2; ++r) {
            float ti0 = ts2[r][c * 8 + i], ti1 = ts2[r][256 + c * 8 + i], ti2 = ts2[r][512 + c * 8 + i];
            // 8-lane-broadcast float4 reads of the three k-chunks (j = 0..7)
            float4 a0 = *(const float4*)&ts2[r][c * 8];
            float4 a1 = *(const float4*)&ts2[r][c * 8 + 4];
            float4 b0 = *(const float4*)&ts2[r][256 + c * 8];
            float4 b1v = *(const float4*)&ts2[r][256 + c * 8 + 4];
            float4 d0 = *(const float4*)&ts2[r][512 + c * 8];
            float4 d1 = *(const float4*)&ts2[r][512 + c * 8 + 4];
            float m0 = (ti0 * a0.x + ti1 * b0.x + ti2 * d0.x) * (1.0f / 3.0f);
            float m1 = (ti0 * a0.y + ti1 * b0.y + ti2 * d0.y) * (1.0f / 3.0f);
            float m2 = (ti0 * a0.z + ti1 * b0.z + ti2 * d0.z) * (1.0f / 3.0f);
            float m3 = (ti0 * a0.w + ti1 * b0.w + ti2 * d0.w) * (1.0f / 3.0f);
            float m4 = (ti0 * a1.x + ti1 * b1v.x + ti2 * d1.x) * (1.0f / 3.0f);
            float m5 = (ti0 * a1.y + ti1 * b1v.y + ti2 * d1.y) * (1.0f / 3.0f);
            float m6 = (ti0 * a1.z + ti1 * b1v.z + ti2 * d1.z) * (1.0f / 3.0f);
            float m7 = (ti0 * a1.w + ti1 * b1v.w + ti2 * d1.w) * (1.0f / 3.0f);
            *(float4*)&mos2[r][c * 68 + i * 8]     = make_float4(m0, m1, m2, m3);
            *(float4*)&mos2[r][c * 68 + i * 8 + 4] = make_float4(m4, m5, m6, m7);
            half8 h8;
            h8[0] = (_Float16)m0; h8[1] = (_Float16)m1; h8[2] = (_Float16)m2; h8[3] = (_Float16)m3;
            h8[4] = (_Float16)m4; h8[5] = (_Float16)m5; h8[6] = (_Float16)m6; h8[7] = (_Float16)m7;
            size_t mobase = ((size_t)(b * 32 + c) * 512 + (l0 + r)) * 64 + i * 8;
            *(half8*)(mo_g + mobase) = h8;
        }
    }
    __syncthreads();

    // ---- GEMM2 (MFMA): mt[d][c] = gelu(Wa . mo_r + ba); 4 n-tiles = 2 rows x 2 c-halves ----
    #pragma unroll
    for (int nt2 = 0; nt2 < 4; ++nt2) {
        const int r = nt2 >> 1, ch = nt2 & 1;
        f32x4 acc = { baq.x, baq.y, baq.z, baq.w };
        #pragma unroll
        for (int ks = 0; ks < 2; ++ks) {
            const float* mp = &mos2[r][(ch * 16 + lr) * 68 + ks * 32 + lk * 8];
            half8 mof = cvt8(*(const float4*)mp, *(const float4*)(mp + 4));
            acc = MFMA_F16(waf[ks], mof, acc);
        }
        half4 o;
        #pragma unroll
        for (int j = 0; j < 4; ++j)
            o[j] = (_Float16)gelu_fast(acc[j]);
        *(half4*)(mt_g + ((size_t)(b * 32 + ch * 16 + lr) * 512 + (l0 + r)) * 64 + w * 16 + lk * 4) = o;
    }
}

// k2 (R4 verbatim — proven local optimum): per (32 l x 16 m) tile:
//   phase A (MFMA): raw[pair][c] -> f16 LDS (pad 40, XOR-swizzled)
//   phase B (MFMA): D[p][pair] = W2 . raw; per-wave LDS transpose ->
//                   8 x 1KB-contiguous nontemporal f32x4 stores per l-row
__global__ __launch_bounds__(256, 2) void k2_mfma(
    const _Float16* __restrict__ mo, const _Float16* __restrict__ mt,
    const float* __restrict__ W2, const float* __restrict__ b2,
    float* __restrict__ out)
{
    __shared__ _Float16 raw16[512 * 40];   // 40 KB
    __shared__ float sc[4][2048];          // 32 KB

    const int tid  = threadIdx.x;
    const int w    = tid >> 6;
    const int lane = tid & 63;
    const int lr   = lane & 15;
    const int lk   = lane >> 4;

    const int flat = blockIdx.x;
    const int nf   = (flat & 7) * 128 + (flat >> 3);
    const int m0   = (nf & 31) << 4;
    const int l0   = ((nf >> 5) & 15) << 5;
    const int b    = nf >> 9;

    #pragma unroll
    for (int cp = 0; cp < 4; ++cp) {
        const int c0 = w * 8 + cp * 2;
        f32x4 acc[2][2] = {};
        #pragma unroll
        for (int ci = 0; ci < 2; ++ci) {
            const int c = c0 + ci;
            const _Float16* mo_c = mo + (((size_t)(b * 32 + c) * 512) + l0) * 64;
            const _Float16* mt_c = mt + (((size_t)(b * 32 + c) * 512) + m0) * 64;
            #pragma unroll
            for (int ks = 0; ks < 2; ++ks) {
                half8 bfrag = *(const half8*)(mt_c + (size_t)lr * 64 + ks * 32 + lk * 8);
                #pragma unroll
                for (int rh = 0; rh < 2; ++rh) {
                    half8 afrag = *(const half8*)(mo_c + (size_t)(rh * 16 + lr) * 64 + ks * 32 + lk * 8);
                    acc[ci][rh] = MFMA_F16(afrag, bfrag, acc[ci][rh]);
                }
            }
        }
        #pragma unroll
        for (int rh = 0; rh < 2; ++rh) {
            #pragma unroll
            for (int j = 0; j < 4; ++j) {
                int pair = (rh * 16 + lk * 4 + j) * 16 + lr;
                int sw   = (((pair >> 3) & 1) << 3) | (((pair >> 6) & 1) << 4);
                *(unsigned*)&raw16[pair * 40 + (c0 ^ sw)] = pack2f16(acc[0][rh][j], acc[1][rh][j]);
            }
        }
    }

    half8 wfrag[8]; float4 b2q[8];
    #pragma unroll
    for (int c8 = 0; c8 < 8; ++c8) {
        const float* wp = W2 + (size_t)(c8 * 16 + lr) * 32 + lk * 8;
        wfrag[c8] = cvt8(*(const float4*)wp, *(const float4*)(wp + 4));
        b2q[c8]   = *(const float4*)(b2 + c8 * 16 + lk * 4);
    }
    __syncthreads();

    for (int i = 0; i < 8; ++i) {
        const int r  = w * 8 + i;
        const int pr = r * 16 + lr;
        const int swr = (((pr >> 3) & 1) << 3) | (((pr >> 6) & 1) << 4);
        half8 a = *(const half8*)&raw16[pr * 40 + ((lk * 8) ^ swr)];

        #pragma unroll
        for (int c8 = 0; c8 < 8; ++c8) {
            f32x4 d = { b2q[c8].x, b2q[c8].y, b2q[c8].z, b2q[c8].w };
            d = MFMA_F16(wfrag[c8], a, d);
            int chunk = (c8 * 4 + lk) ^ lr;
            *(f32x4*)&sc[w][lr * 128 + chunk * 4] = d;
        }
        float* ob = out + (((size_t)(b * 512 + l0 + r)) * 512 + m0) * 128;
        #pragma unroll
        for (int s = 0; s < 8; ++s) {
            int mm = s * 2 + (lane >> 5);
            int cp = (lane & 31) ^ mm;
            f32x4 v = *(const f32x4*)&sc[w][mm * 128 + cp * 4];
            __builtin_nontemporal_store(v, (f32x4*)(ob + s * 256 + lane * 4));
        }
    }
}

extern "C" void kernel_launch(void* const* d_in, const int* in_sizes, int n_in,
                              void* d_out, int out_size, void* d_ws, size_t ws_size,
                              hipStream_t stream) {
    const float* x    = (const float*)d_in[0];
    const float* ln_w = (const float*)d_in[1];
    const float* ln_b = (const float*)d_in[2];
    const float* W1   = (const float*)d_in[3];
    const float* b1   = (const float*)d_in[4];
    const float* Wa   = (const float*)d_in[5];
    const float* ba   = (const float*)d_in[6];
    const float* W2   = (const float*)d_in[7];
    const float* b2   = (const float*)d_in[8];
    float* out = (float*)d_out;

    _Float16* mo  = (_Float16*)d_ws;                     // 4 MB
    _Float16* mt  = mo + (size_t)2 * 32 * 512 * 64;      // 4 MB
    _Float16* W1H = mt + (size_t)2 * 32 * 512 * 64;      // 128 KB

    k0_pack<<<32, 256, 0, stream>>>(W1, W1H);
    k1_rowstage2<<<512, 256, 0, stream>>>(x, ln_w, ln_b, W1H, b1, Wa, ba, mo, mt);
    k2_mfma<<<1024, 256, 0, stream>>>(mo, mt, W2, b2, out);
}